// Round 6
// baseline (197.930 us; speedup 1.0000x reference)
//
#include <hip/hip_runtime.h>
#include <hip/hip_bf16.h>

#define Bdim 16
#define Ndim 1024
#define Hh   4
#define HDc  128
#define L2E  1.4426950408889634f

typedef float  float4v  __attribute__((ext_vector_type(4)));
typedef short  short8   __attribute__((ext_vector_type(8)));
typedef unsigned short ushort4v __attribute__((ext_vector_type(4)));

__device__ __forceinline__ unsigned short bf16_rne(float f) {
    unsigned u = __float_as_uint(f);
    u = u + 0x7FFFu + ((u >> 16) & 1u);
    return (unsigned short)(u >> 16);
}

__device__ __forceinline__ void gl_lds16(const void* g, void* l) {
    __builtin_amdgcn_global_load_lds(
        (const __attribute__((address_space(1))) unsigned int*)g,
        (__attribute__((address_space(3))) unsigned int*)l, 16, 0, 0);
}

// ---------- split_w: WT hi/lo [144][128] row-major + bias2[144] -------------
// rows 0..127: W^T; 128..131: (W@a_i)^T*log2e; 132..135: (W@a_j)^T*log2e; pad 0.
__global__ __launch_bounds__(256) void split_w_kernel(
    const float* __restrict__ W, const float* __restrict__ bias,
    const float* __restrict__ a,
    unsigned short* __restrict__ WTh, unsigned short* __restrict__ WTl,
    float* __restrict__ bias2)
{
    const int t = threadIdx.x, blk = blockIdx.x;
    if (blk < 16) {
        int r  = blk * 8 + (t >> 5);
        int k0 = (t & 31) * 4;
        #pragma unroll
        for (int j = 0; j < 4; ++j) {
            float f = W[(size_t)(k0 + j) * HDc + r];
            unsigned short hi = bf16_rne(f);
            WTh[r * 128 + k0 + j] = hi;
            WTl[r * 128 + k0 + j] = bf16_rne(f - __uint_as_float((unsigned)hi << 16));
        }
    } else {
        #pragma unroll
        for (int rep = 0; rep < 2; ++rep) {
            int task = t + rep * 256;          // (row, hh): 512 tasks
            int row = task >> 2, hh = task & 3;
            float si = 0.f, sj = 0.f;
            #pragma unroll
            for (int d4 = 0; d4 < 8; ++d4) {
                float4v wv = *(const float4v*)(W + (size_t)row * HDc + hh * 32 + d4 * 4);
                float4v av = *(const float4v*)(a + d4 * 4);
                float4v bv = *(const float4v*)(a + 32 + d4 * 4);
                #pragma unroll
                for (int kk = 0; kk < 4; ++kk) {
                    si = fmaf(wv[kk], av[kk], si);
                    sj = fmaf(wv[kk], bv[kk], sj);
                }
            }
            float vi = si * L2E, vj = sj * L2E;
            unsigned short hi = bf16_rne(vi);
            WTh[(128 + hh) * 128 + row] = hi;
            WTl[(128 + hh) * 128 + row] = bf16_rne(vi - __uint_as_float((unsigned)hi << 16));
            unsigned short hj = bf16_rne(vj);
            WTh[(132 + hh) * 128 + row] = hj;
            WTl[(132 + hh) * 128 + row] = bf16_rne(vj - __uint_as_float((unsigned)hj << 16));
        }
        #pragma unroll
        for (int rp = 0; rp < 4; ++rp) {
            int idx = t + rp * 256;            // pad rows 136..143
            WTh[136 * 128 + idx] = 0;
            WTl[136 * 128 + idx] = 0;
        }
        if (t < 128) {
            bias2[t] = bias[t];
        } else if (t < 136) {
            int z = t - 128;
            const float* av = (z < 4) ? a : a + 32;
            int hh = z & 3;
            float s = 0.f;
            for (int d = 0; d < 32; ++d) s = fmaf(bias[hh * 32 + d], av[d], s);
            bias2[128 + z] = s * L2E;
        } else if (t < 144) {
            bias2[t] = 0.f;
        }
    }
}

// ---------- proj: [h|ei|ej] = x @ [W|wa_i|wa_j], all operands in LDS --------
// block = 128 rows; wave = 32 rows (two 16-row A-groups). Grid 128.
__global__ __launch_bounds__(256, 1) void proj_kernel(
    const float* __restrict__ x,
    const unsigned short* __restrict__ WTg_h, const unsigned short* __restrict__ WTg_l,
    const float* __restrict__ bias2,
    unsigned short* __restrict__ hTh, float* __restrict__ eiT, float* __restrict__ ejT)
{
    __shared__ unsigned char smem[139264];     // xs 64K | WT 72K
    char* xls  = (char*)smem;
    char* wtls = (char*)smem + 65536;

    const int t = threadIdx.x, lane = t & 63, w = t >> 6;
    const int l16 = lane & 15, q = lane >> 4;
    const int nb = blockIdx.x * 128;
    const int b = nb >> 10, nloc = nb & 1023;

    // ---- stage x: wave stages its own 32 rows (512B each), chunk ^ (row&7)
    {
        const char* gx = (const char*)(x + (size_t)nb * 128);
        int rh = lane >> 5, m = lane & 31;
        #pragma unroll
        for (int d = 0; d < 16; ++d) {
            int r = w * 32 + d * 2 + rh;
            int mg = m ^ (r & 7);
            gl_lds16(gx + (size_t)r * 512 + mg * 16, xls + (size_t)w * 16384 + d * 1024);
        }
    }
    // ---- stage WT hi+lo (72KB, cross-wave), chunk ^ (row&15)
    {
        int rh = lane >> 4, m = lane & 15;
        #pragma unroll
        for (int d = 0; d < 18; ++d) {
            int n = w * 18 + d;
            if (n < 36) {
                int r = n * 4 + rh;
                gl_lds16((const char*)WTg_h + (size_t)r * 256 + (m ^ (r & 15)) * 16,
                         wtls + (size_t)n * 1024);
            } else {
                int r = (n - 36) * 4 + rh;
                gl_lds16((const char*)WTg_l + (size_t)r * 256 + (m ^ (r & 15)) * 16,
                         wtls + (size_t)n * 1024);
            }
        }
    }
    __syncthreads();   // drains vmcnt

    float4v C[2][9];
    #pragma unroll
    for (int g = 0; g < 2; ++g)
        #pragma unroll
        for (int nt = 0; nt < 9; ++nt) C[g][nt] = (float4v){0.f, 0.f, 0.f, 0.f};

    #pragma unroll
    for (int ks = 0; ks < 4; ++ks) {
        short8 Ah[2], Al[2];
        #pragma unroll
        for (int g = 0; g < 2; ++g) {
            int r = w * 32 + g * 16 + l16;
            int c0 = (ks * 8 + q * 2) ^ (l16 & 7);
            int c1 = (ks * 8 + q * 2 + 1) ^ (l16 & 7);
            float4v x0 = *(const float4v*)(xls + (size_t)r * 512 + c0 * 16);
            float4v x1 = *(const float4v*)(xls + (size_t)r * 512 + c1 * 16);
            #pragma unroll
            for (int e = 0; e < 8; ++e) {
                float f = (e < 4) ? x0[e] : x1[e - 4];
                unsigned short hi = bf16_rne(f);
                Ah[g][e] = (short)hi;
                Al[g][e] = (short)bf16_rne(f - __uint_as_float((unsigned)hi << 16));
            }
        }
        #pragma unroll
        for (int nt = 0; nt < 9; ++nt) {
            const char* wb = wtls + (size_t)(nt * 16 + l16) * 256 + ((ks * 4 + q) ^ l16) * 16;
            short8 Bh = *(const short8*)wb;
            short8 Bl = *(const short8*)(wb + 36864);
            #pragma unroll
            for (int g = 0; g < 2; ++g) {
                C[g][nt] = __builtin_amdgcn_mfma_f32_16x16x32_bf16(Ah[g], Bh, C[g][nt], 0, 0, 0);
                C[g][nt] = __builtin_amdgcn_mfma_f32_16x16x32_bf16(Ah[g], Bl, C[g][nt], 0, 0, 0);
                C[g][nt] = __builtin_amdgcn_mfma_f32_16x16x32_bf16(Al[g], Bh, C[g][nt], 0, 0, 0);
            }
        }
    }

    // ---- epilogue: bias, bf16 h-store (transposed), e-columns
    #pragma unroll
    for (int g = 0; g < 2; ++g) {
        int node = nloc + w * 32 + g * 16 + q * 4;
        #pragma unroll
        for (int nt = 0; nt < 8; ++nt) {
            int col = nt * 16 + l16;
            float bv = bias2[col];
            ushort4v h4;
            #pragma unroll
            for (int r = 0; r < 4; ++r) h4[r] = bf16_rne(C[g][nt][r] + bv);
            *(ushort4v*)(hTh + (size_t)(b * HDc + col) * Ndim + node) = h4;
        }
        float bv = bias2[128 + l16];
        float4v v = {C[g][8][0] + bv, C[g][8][1] + bv, C[g][8][2] + bv, C[g][8][3] + bv};
        if (l16 < 4)
            *(float4v*)(eiT + (size_t)(b * Hh + l16) * Ndim + node) = v;
        else if (l16 < 8)
            *(float4v*)(ejT + (size_t)(b * Hh + (l16 - 4)) * Ndim + node) = v;
    }
}

// ---------- gat: fused adj-pack + score + MFMA PV -----------------------------
// block = 32 i-rows x 4 heads (wave = head), grid 512 (2 blocks/CU).
__global__ __launch_bounds__(256, 2) void gat_kernel(
    const int* __restrict__ adj, const unsigned short* __restrict__ hTh,
    const float* __restrict__ eiT, const float* __restrict__ ejT,
    float* __restrict__ out)
{
    __shared__ unsigned char smem[45056];      // pk 4K | ej 16K | rings 4x6K
    unsigned int* pkl = (unsigned int*)smem;
    float* ejl = (float*)(smem + 4096);
    char* rings = (char*)smem + 20480;

    const int t = threadIdx.x, lane = t & 63, w = t >> 6;
    const int L = blockIdx.x;
    const int b = (L & 7) + 8 * ((L >> 3) & 1);          // batch -> XCD pinning
    const int ibase = (L >> 4) * 32;
    const int i = lane & 15, q = lane >> 4;

    // ---- phase A: pack rows w*8..w*8+7 (contiguous 256B reads, once from HBM)
    {
        const int* arow = adj + ((size_t)(b * Ndim + ibase + w * 8)) * Ndim + lane;
        #pragma unroll
        for (int rl = 0; rl < 8; ++rl) {
            int r = w * 8 + rl;
            #pragma unroll
            for (int c = 0; c < 16; ++c) {
                int v = __builtin_nontemporal_load(arow + (size_t)rl * Ndim + c * 64);
                unsigned long long m = __ballot(v > 0);
                if (lane == 0)  pkl[r * 32 + ((2 * c + r) & 31)]     = (unsigned)m;
                if (lane == 32) pkl[r * 32 + ((2 * c + 1 + r) & 31)] = (unsigned)(m >> 32);
            }
        }
    }
    const float ei0 = eiT[(size_t)(b * Hh + w) * Ndim + ibase + i];
    const float ei1 = eiT[(size_t)(b * Hh + w) * Ndim + ibase + 16 + i];
    __syncthreads();   // pk visible to all waves; vmcnt drained

    // ---- ej DMA: wave's head row (4KB). NOTE: source MUST be per-lane
    // (global_load_lds = per-lane gaddr -> uniform LDS base + lane*16).
    {
        const char* gej = (const char*)(ejT + (size_t)(b * Hh + w) * Ndim);
        #pragma unroll
        for (int c = 0; c < 4; ++c)
            gl_lds16(gej + c * 1024 + lane * 16, (char*)(ejl + w * 1024) + c * 1024);
    }

    // ---- hT ring: 3 slots x 2KB per wave; slot = [d 0..15][64B] + [d 16..31]
    const char* gh = (const char*)(hTh + (size_t)(b * HDc + w * 32) * Ndim);
    const size_t lane_g = (size_t)(lane >> 2) * 2048 + (lane & 3) * 16;
    char* ringw = rings + w * 6144;

#define ISSUE(JT, SLOT) {                                                   \
    char* lb_ = ringw + (SLOT) * 2048;                                      \
    gl_lds16(gh + (size_t)(JT) * 64 + lane_g,         lb_);                 \
    gl_lds16(gh + 32768 + (size_t)(JT) * 64 + lane_g, lb_ + 1024); }

    ISSUE(0, 0); ISSUE(1, 1);

    float4v C0[2], C1[2];
    #pragma unroll
    for (int it = 0; it < 2; ++it) {
        C0[it] = (float4v){0.f, 0.f, 0.f, 0.f};
        C1[it] = (float4v){0.f, 0.f, 0.f, 0.f};
    }
    float den[2] = {0.f, 0.f};
    const float* ejw = ejl + w * 1024;

    int slot_c = 0;
    for (int jt = 0; jt < 32; ++jt) {
        int ji = jt + 2; if (ji > 31) ji = 31;
        int slot_i = slot_c + 2; if (slot_i >= 3) slot_i -= 3;
        ISSUE(ji, slot_i);
        asm volatile("s_waitcnt vmcnt(4)" ::: "memory");

        const char* lb = ringw + slot_c * 2048;
        short8 Bh0 = *(const short8*)(lb + i * 64 + q * 16);
        short8 Bh1 = *(const short8*)(lb + 1024 + i * 64 + q * 16);
        float4v e0 = *(const float4v*)(ejw + jt * 32 + q * 8);
        float4v e1 = *(const float4v*)(ejw + jt * 32 + q * 8 + 4);

        #pragma unroll
        for (int it = 0; it < 2; ++it) {
            int r = it * 16 + i;
            unsigned bits = (pkl[r * 32 + ((jt + r) & 31)] >> (q * 8)) & 0xffu;
            float my_ei = it ? ei1 : ei0;
            float p[8];
            #pragma unroll
            for (int k = 0; k < 8; ++k) {
                float ev = (k < 4) ? e0[k] : e1[k - 4];
                float e = my_ei + ev;                 // already * log2e
                float sL = fmaxf(e, 0.2f * e);        // leaky = max(e, 0.2e)
                float pe = ((bits >> k) & 1u) ? __builtin_amdgcn_exp2f(sL) : 0.f;
                den[it] += pe;
                p[k] = pe;
            }
            union { __hip_bfloat162 h2[4]; short8 s8; } A;
            #pragma unroll
            for (int k2 = 0; k2 < 4; ++k2)
                A.h2[k2] = __float22bfloat162_rn(make_float2(p[2 * k2], p[2 * k2 + 1]));
            C0[it] = __builtin_amdgcn_mfma_f32_16x16x32_bf16(A.s8, Bh0, C0[it], 0, 0, 0);
            C1[it] = __builtin_amdgcn_mfma_f32_16x16x32_bf16(A.s8, Bh1, C1[it], 0, 0, 0);
        }
        slot_c = (slot_c == 2) ? 0 : slot_c + 1;
    }
#undef ISSUE

    #pragma unroll
    for (int it = 0; it < 2; ++it) {
        float d_ = den[it];
        d_ += __shfl_xor(d_, 16);
        d_ += __shfl_xor(d_, 32);
        den[it] = d_;
    }
    // C/D layout: col = lane&15 (feature), row = q*4+reg (node)
    float* outp = out + ((size_t)(b * Ndim + ibase)) * HDc + w * 32 + i;
    #pragma unroll
    for (int it = 0; it < 2; ++it) {
        #pragma unroll
        for (int reg = 0; reg < 4; ++reg) {
            int row = it * 16 + q * 4 + reg;
            float rd = 1.0f / __shfl(den[it], q * 4 + reg, 64);
            outp[(size_t)row * HDc]      = C0[it][reg] * rd;
            outp[(size_t)row * HDc + 16] = C1[it][reg] * rd;
        }
    }
}

extern "C" void kernel_launch(void* const* d_in, const int* in_sizes, int n_in,
                              void* d_out, int out_size, void* d_ws, size_t ws_size,
                              hipStream_t stream) {
    const float* x    = (const float*)d_in[0];
    const int*   adj  = (const int*)d_in[1];
    const float* W    = (const float*)d_in[2];
    const float* bias = (const float*)d_in[3];
    const float* a    = (const float*)d_in[4];
    float* out = (float*)d_out;

    // ws: hTh 4MB | eiT 256K | ejT 256K | WTh 36K | WTl 36K | bias2
    unsigned short* hTh = (unsigned short*)d_ws;
    float* eiT = (float*)(hTh + (size_t)Bdim * HDc * Ndim);
    float* ejT = eiT + (size_t)Bdim * Hh * Ndim;
    unsigned short* WTh = (unsigned short*)(ejT + (size_t)Bdim * Hh * Ndim);
    unsigned short* WTl = WTh + 144 * 128;
    float* bias2 = (float*)(WTl + 144 * 128);

    split_w_kernel<<<dim3(17), dim3(256), 0, stream>>>(W, bias, a, WTh, WTl, bias2);
    proj_kernel<<<dim3(128), dim3(256), 0, stream>>>(
        x, WTh, WTl, bias2, hTh, eiT, ejT);
    gat_kernel<<<dim3(512), dim3(256), 0, stream>>>(
        adj, hTh, eiT, ejT, out);
}

// Round 7
// 168.989 us; speedup vs baseline: 1.1713x; 1.1713x over previous
//
#include <hip/hip_runtime.h>
#include <hip/hip_bf16.h>

#define Bdim 16
#define Ndim 1024
#define Hh   4
#define HDc  128
#define L2E  1.4426950408889634f

typedef float  float4v  __attribute__((ext_vector_type(4)));
typedef int    int4v    __attribute__((ext_vector_type(4)));
typedef short  short8   __attribute__((ext_vector_type(8)));
typedef unsigned short ushort4v __attribute__((ext_vector_type(4)));

__device__ __forceinline__ unsigned short bf16_rne(float f) {
    unsigned u = __float_as_uint(f);
    u = u + 0x7FFFu + ((u >> 16) & 1u);
    return (unsigned short)(u >> 16);
}

__device__ __forceinline__ void gl_lds16(const void* g, void* l) {
    __builtin_amdgcn_global_load_lds(
        (const __attribute__((address_space(1))) unsigned int*)g,
        (__attribute__((address_space(3))) unsigned int*)l, 16, 0, 0);
}

// ---------- split_w: WT hi/lo [144][128] row-major + bias2[144] -------------
__global__ __launch_bounds__(256) void split_w_kernel(
    const float* __restrict__ W, const float* __restrict__ bias,
    const float* __restrict__ a,
    unsigned short* __restrict__ WTh, unsigned short* __restrict__ WTl,
    float* __restrict__ bias2)
{
    const int t = threadIdx.x, blk = blockIdx.x;
    if (blk < 16) {
        int r  = blk * 8 + (t >> 5);
        int k0 = (t & 31) * 4;
        #pragma unroll
        for (int j = 0; j < 4; ++j) {
            float f = W[(size_t)(k0 + j) * HDc + r];
            unsigned short hi = bf16_rne(f);
            WTh[r * 128 + k0 + j] = hi;
            WTl[r * 128 + k0 + j] = bf16_rne(f - __uint_as_float((unsigned)hi << 16));
        }
    } else {
        #pragma unroll
        for (int rep = 0; rep < 2; ++rep) {
            int task = t + rep * 256;
            int row = task >> 2, hh = task & 3;
            float si = 0.f, sj = 0.f;
            #pragma unroll
            for (int d4 = 0; d4 < 8; ++d4) {
                float4v wv = *(const float4v*)(W + (size_t)row * HDc + hh * 32 + d4 * 4);
                float4v av = *(const float4v*)(a + d4 * 4);
                float4v bv = *(const float4v*)(a + 32 + d4 * 4);
                #pragma unroll
                for (int kk = 0; kk < 4; ++kk) {
                    si = fmaf(wv[kk], av[kk], si);
                    sj = fmaf(wv[kk], bv[kk], sj);
                }
            }
            float vi = si * L2E, vj = sj * L2E;
            unsigned short hi = bf16_rne(vi);
            WTh[(128 + hh) * 128 + row] = hi;
            WTl[(128 + hh) * 128 + row] = bf16_rne(vi - __uint_as_float((unsigned)hi << 16));
            unsigned short hj = bf16_rne(vj);
            WTh[(132 + hh) * 128 + row] = hj;
            WTl[(132 + hh) * 128 + row] = bf16_rne(vj - __uint_as_float((unsigned)hj << 16));
        }
        #pragma unroll
        for (int rp = 0; rp < 4; ++rp) {
            int idx = t + rp * 256;
            WTh[136 * 128 + idx] = 0;
            WTl[136 * 128 + idx] = 0;
        }
        if (t < 128) {
            bias2[t] = bias[t];
        } else if (t < 136) {
            int z = t - 128;
            const float* av = (z < 4) ? a : a + 32;
            int hh = z & 3;
            float s = 0.f;
            for (int d = 0; d < 32; ++d) s = fmaf(bias[hh * 32 + d], av[d], s);
            bias2[128 + z] = s * L2E;
        } else if (t < 144) {
            bias2[t] = 0.f;
        }
    }
}

// ---------- proj: [h|ei|ej] = x @ [W|wa_i|wa_j]; 64 rows/block, grid 256 ----
__global__ __launch_bounds__(256, 1) void proj_kernel(
    const float* __restrict__ x,
    const unsigned short* __restrict__ WTg_h, const unsigned short* __restrict__ WTg_l,
    const float* __restrict__ bias2,
    unsigned short* __restrict__ hTh, float* __restrict__ eiT, float* __restrict__ ejT)
{
    __shared__ __align__(16) unsigned char smem[106496];  // xs 32K | WT 72K
    char* xls  = (char*)smem;
    char* wtls = (char*)smem + 32768;

    const int t = threadIdx.x, lane = t & 63, w = t >> 6;
    const int l16 = lane & 15, q = lane >> 4;
    const int nb = blockIdx.x * 64;
    const int b = nb >> 10, nloc = nb & 1023;

    // ---- stage x: wave stages its own 16 rows (512B each), chunk ^ (row&7)
    {
        const char* gx = (const char*)(x + (size_t)nb * 128);
        int rh = lane >> 5, m = lane & 31;
        #pragma unroll
        for (int d = 0; d < 8; ++d) {
            int r = w * 16 + d * 2 + rh;
            int mg = m ^ (r & 7);
            gl_lds16(gx + (size_t)r * 512 + mg * 16, xls + (size_t)w * 8192 + d * 1024);
        }
    }
    // ---- stage WT hi+lo (72KB, cross-wave), chunk ^ (row&15)
    {
        int rh = lane >> 4, m = lane & 15;
        #pragma unroll
        for (int d = 0; d < 18; ++d) {
            int n = w * 18 + d;
            if (n < 36) {
                int r = n * 4 + rh;
                gl_lds16((const char*)WTg_h + (size_t)r * 256 + (m ^ (r & 15)) * 16,
                         wtls + (size_t)n * 1024);
            } else {
                int r = (n - 36) * 4 + rh;
                gl_lds16((const char*)WTg_l + (size_t)r * 256 + (m ^ (r & 15)) * 16,
                         wtls + (size_t)n * 1024);
            }
        }
    }
    __syncthreads();   // drains vmcnt

    float4v C[9];
    #pragma unroll
    for (int nt = 0; nt < 9; ++nt) C[nt] = (float4v){0.f, 0.f, 0.f, 0.f};

    #pragma unroll
    for (int ks = 0; ks < 4; ++ks) {
        short8 Ah, Al;
        {
            int r = w * 16 + l16;
            int c0 = (ks * 8 + q * 2) ^ (l16 & 7);
            int c1 = (ks * 8 + q * 2 + 1) ^ (l16 & 7);
            float4v x0 = *(const float4v*)(xls + (size_t)r * 512 + c0 * 16);
            float4v x1 = *(const float4v*)(xls + (size_t)r * 512 + c1 * 16);
            #pragma unroll
            for (int e = 0; e < 8; ++e) {
                float f = (e < 4) ? x0[e] : x1[e - 4];
                unsigned short hi = bf16_rne(f);
                Ah[e] = (short)hi;
                Al[e] = (short)bf16_rne(f - __uint_as_float((unsigned)hi << 16));
            }
        }
        #pragma unroll
        for (int nt = 0; nt < 9; ++nt) {
            const char* wb = wtls + (size_t)(nt * 16 + l16) * 256 + ((ks * 4 + q) ^ l16) * 16;
            short8 Bh = *(const short8*)wb;
            short8 Bl = *(const short8*)(wb + 36864);
            C[nt] = __builtin_amdgcn_mfma_f32_16x16x32_bf16(Ah, Bh, C[nt], 0, 0, 0);
            C[nt] = __builtin_amdgcn_mfma_f32_16x16x32_bf16(Ah, Bl, C[nt], 0, 0, 0);
            C[nt] = __builtin_amdgcn_mfma_f32_16x16x32_bf16(Al, Bh, C[nt], 0, 0, 0);
        }
    }

    // ---- epilogue
    {
        int node = nloc + w * 16 + q * 4;
        #pragma unroll
        for (int nt = 0; nt < 8; ++nt) {
            int col = nt * 16 + l16;
            float bv = bias2[col];
            ushort4v h4;
            #pragma unroll
            for (int r = 0; r < 4; ++r) h4[r] = bf16_rne(C[nt][r] + bv);
            *(ushort4v*)(hTh + (size_t)(b * HDc + col) * Ndim + node) = h4;
        }
        float bv = bias2[128 + l16];
        float4v v = {C[8][0] + bv, C[8][1] + bv, C[8][2] + bv, C[8][3] + bv};
        if (l16 < 4)
            *(float4v*)(eiT + (size_t)(b * Hh + l16) * Ndim + node) = v;
        else if (l16 < 8)
            *(float4v*)(ejT + (size_t)(b * Hh + (l16 - 4)) * Ndim + node) = v;
    }
}

// ---------- gat: 16 i-rows x 4 heads, grid 1024; batched in-lane adj pack ---
__global__ __launch_bounds__(256, 4) void gat_kernel(
    const int* __restrict__ adj, const unsigned short* __restrict__ hTh,
    const float* __restrict__ eiT, const float* __restrict__ ejT,
    float* __restrict__ out)
{
    __shared__ __align__(16) unsigned char smem[26624];  // pk 2K | rings 4x6K
    unsigned int* pkl = (unsigned int*)smem;
    char* rings = (char*)smem + 2048;

    const int t = threadIdx.x, lane = t & 63, w = t >> 6;
    const int L = blockIdx.x;
    const int b = (L & 7) + 8 * ((L >> 3) & 1);          // batch -> XCD pinning
    const int ibase = (L >> 4) * 16;
    const int i = lane & 15, q = lane >> 4;

    // ---- phase A: in-lane pack (adj values are 0/1 by construction).
    // Wave w packs rows w*4..w*4+3. Lane: row = w*4+p*2+(lane>>5), word m=lane&31
    // holds ints [m*32, m*32+32). 16 independent int4 loads, then pure VALU.
    {
        const int m = lane & 31, rh = lane >> 5;
        const int r0 = w * 4 + rh;          // pass 0 row
        const int r1 = w * 4 + 2 + rh;      // pass 1 row
        const int4v* s0 = (const int4v*)(adj + ((size_t)(b * Ndim + ibase + r0)) * Ndim + m * 32);
        const int4v* s1 = (const int4v*)(adj + ((size_t)(b * Ndim + ibase + r1)) * Ndim + m * 32);
        int4v va[8], vb[8];
        #pragma unroll
        for (int u = 0; u < 8; ++u) va[u] = __builtin_nontemporal_load(s0 + u);
        #pragma unroll
        for (int u = 0; u < 8; ++u) vb[u] = __builtin_nontemporal_load(s1 + u);
        unsigned wa = 0, wb_ = 0;
        #pragma unroll
        for (int u = 0; u < 8; ++u) {
            unsigned na = (unsigned)(va[u][0] | (va[u][1] << 1) | (va[u][2] << 2) | (va[u][3] << 3));
            unsigned nb_ = (unsigned)(vb[u][0] | (vb[u][1] << 1) | (vb[u][2] << 2) | (vb[u][3] << 3));
            wa  |= na  << (4 * u);
            wb_ |= nb_ << (4 * u);
        }
        pkl[r0 * 32 + ((m + r0) & 31)] = wa;   // +row rotation kills bank alias
        pkl[r1 * 32 + ((m + r1) & 31)] = wb_;
    }
    const float my_ei = eiT[(size_t)(b * Hh + w) * Ndim + ibase + i];
    __syncthreads();   // pk visible to all waves; vmcnt drained

    // ---- hT ring: 3 slots x 2KB per wave
    const char* gh = (const char*)(hTh + (size_t)(b * HDc + w * 32) * Ndim);
    const float* ej_p = ejT + (size_t)(b * Hh + w) * Ndim + q * 8;
    const size_t lane_g = (size_t)(lane >> 2) * 2048 + (lane & 3) * 16;
    char* ringw = rings + w * 6144;

#define ISSUE(JT, SLOT) {                                                   \
    char* lb_ = ringw + (SLOT) * 2048;                                      \
    gl_lds16(gh + (size_t)(JT) * 64 + lane_g,         lb_);                 \
    gl_lds16(gh + 32768 + (size_t)(JT) * 64 + lane_g, lb_ + 1024); }

    ISSUE(0, 0); ISSUE(1, 1);

    float4v C0 = {0.f, 0.f, 0.f, 0.f};
    float4v C1 = {0.f, 0.f, 0.f, 0.f};
    float den_a = 0.f, den_b = 0.f;

    int slot_c = 0;
    for (int jt = 0; jt < 32; ++jt) {
        int ji = jt + 2; if (ji > 31) ji = 31;
        int slot_i = slot_c + 2; if (slot_i >= 3) slot_i -= 3;
        ISSUE(ji, slot_i);
        asm volatile("s_waitcnt vmcnt(4)" ::: "memory");

        const char* lb = ringw + slot_c * 2048;
        short8 Bh0 = *(const short8*)(lb + i * 64 + q * 16);
        short8 Bh1 = *(const short8*)(lb + 1024 + i * 64 + q * 16);
        float4v e0 = *(const float4v*)(ej_p + jt * 32);
        float4v e1 = *(const float4v*)(ej_p + jt * 32 + 4);

        unsigned bits = (pkl[i * 32 + ((jt + i) & 31)] >> (q * 8)) & 0xffu;
        float p[8];
        #pragma unroll
        for (int k = 0; k < 8; ++k) {
            float ev = (k < 4) ? e0[k] : e1[k - 4];
            float e = my_ei + ev;                 // already * log2e
            float sL = fmaxf(e, 0.2f * e);        // leaky = max(e, 0.2e)
            float pe = ((bits >> k) & 1u) ? __builtin_amdgcn_exp2f(sL) : 0.f;
            if (k & 1) den_b += pe; else den_a += pe;
            p[k] = pe;
        }
        union { __hip_bfloat162 h2[4]; short8 s8; } A;
        #pragma unroll
        for (int k2 = 0; k2 < 4; ++k2)
            A.h2[k2] = __float22bfloat162_rn(make_float2(p[2 * k2], p[2 * k2 + 1]));
        C0 = __builtin_amdgcn_mfma_f32_16x16x32_bf16(A.s8, Bh0, C0, 0, 0, 0);
        C1 = __builtin_amdgcn_mfma_f32_16x16x32_bf16(A.s8, Bh1, C1, 0, 0, 0);
        slot_c = (slot_c == 2) ? 0 : slot_c + 1;
    }
#undef ISSUE

    float den = den_a + den_b;
    den += __shfl_xor(den, 16);
    den += __shfl_xor(den, 32);

    // C/D layout: col = lane&15 (feature), row = q*4+reg (node)
    float* outp = out + ((size_t)(b * Ndim + ibase)) * HDc + w * 32 + i;
    #pragma unroll
    for (int reg = 0; reg < 4; ++reg) {
        int row = q * 4 + reg;
        float rd = 1.0f / __shfl(den, row, 64);
        outp[(size_t)row * HDc]      = C0[reg] * rd;
        outp[(size_t)row * HDc + 16] = C1[reg] * rd;
    }
}

extern "C" void kernel_launch(void* const* d_in, const int* in_sizes, int n_in,
                              void* d_out, int out_size, void* d_ws, size_t ws_size,
                              hipStream_t stream) {
    const float* x    = (const float*)d_in[0];
    const int*   adj  = (const int*)d_in[1];
    const float* W    = (const float*)d_in[2];
    const float* bias = (const float*)d_in[3];
    const float* a    = (const float*)d_in[4];
    float* out = (float*)d_out;

    // ws: hTh 4MB | eiT 256K | ejT 256K | WTh 36K | WTl 36K | bias2
    unsigned short* hTh = (unsigned short*)d_ws;
    float* eiT = (float*)(hTh + (size_t)Bdim * HDc * Ndim);
    float* ejT = eiT + (size_t)Bdim * Hh * Ndim;
    unsigned short* WTh = (unsigned short*)(ejT + (size_t)Bdim * Hh * Ndim);
    unsigned short* WTl = WTh + 144 * 128;
    float* bias2 = (float*)(WTl + 144 * 128);

    split_w_kernel<<<dim3(17), dim3(256), 0, stream>>>(W, bias, a, WTh, WTl, bias2);
    proj_kernel<<<dim3(256), dim3(256), 0, stream>>>(
        x, WTh, WTl, bias2, hTh, eiT, ejT);
    gat_kernel<<<dim3(1024), dim3(256), 0, stream>>>(
        adj, hTh, eiT, ejT, out);
}

// Round 8
// 166.270 us; speedup vs baseline: 1.1904x; 1.0164x over previous
//
#include <hip/hip_runtime.h>
#include <hip/hip_bf16.h>

#define Bdim 16
#define Ndim 1024
#define Hh   4
#define HDc  128
#define L2E  1.4426950408889634f

typedef float  float4v  __attribute__((ext_vector_type(4)));
typedef int    int4v    __attribute__((ext_vector_type(4)));
typedef short  short8   __attribute__((ext_vector_type(8)));
typedef unsigned short ushort4v __attribute__((ext_vector_type(4)));

__device__ __forceinline__ unsigned short bf16_rne(float f) {
    unsigned u = __float_as_uint(f);
    u = u + 0x7FFFu + ((u >> 16) & 1u);
    return (unsigned short)(u >> 16);
}

__device__ __forceinline__ void gl_lds16(const void* g, void* l) {
    __builtin_amdgcn_global_load_lds(
        (const __attribute__((address_space(1))) unsigned int*)g,
        (__attribute__((address_space(3))) unsigned int*)l, 16, 0, 0);
}

// ---------- split_w: WT hi/lo [144][128] row-major + bias2[144] -------------
__global__ __launch_bounds__(256) void split_w_kernel(
    const float* __restrict__ W, const float* __restrict__ bias,
    const float* __restrict__ a,
    unsigned short* __restrict__ WTh, unsigned short* __restrict__ WTl,
    float* __restrict__ bias2)
{
    const int t = threadIdx.x, blk = blockIdx.x;
    if (blk < 16) {
        int r  = blk * 8 + (t >> 5);
        int k0 = (t & 31) * 4;
        #pragma unroll
        for (int j = 0; j < 4; ++j) {
            float f = W[(size_t)(k0 + j) * HDc + r];
            unsigned short hi = bf16_rne(f);
            WTh[r * 128 + k0 + j] = hi;
            WTl[r * 128 + k0 + j] = bf16_rne(f - __uint_as_float((unsigned)hi << 16));
        }
    } else {
        #pragma unroll
        for (int rep = 0; rep < 2; ++rep) {
            int task = t + rep * 256;
            int row = task >> 2, hh = task & 3;
            float si = 0.f, sj = 0.f;
            #pragma unroll
            for (int d4 = 0; d4 < 8; ++d4) {
                float4v wv = *(const float4v*)(W + (size_t)row * HDc + hh * 32 + d4 * 4);
                float4v av = *(const float4v*)(a + d4 * 4);
                float4v bv = *(const float4v*)(a + 32 + d4 * 4);
                #pragma unroll
                for (int kk = 0; kk < 4; ++kk) {
                    si = fmaf(wv[kk], av[kk], si);
                    sj = fmaf(wv[kk], bv[kk], sj);
                }
            }
            float vi = si * L2E, vj = sj * L2E;
            unsigned short hi = bf16_rne(vi);
            WTh[(128 + hh) * 128 + row] = hi;
            WTl[(128 + hh) * 128 + row] = bf16_rne(vi - __uint_as_float((unsigned)hi << 16));
            unsigned short hj = bf16_rne(vj);
            WTh[(132 + hh) * 128 + row] = hj;
            WTl[(132 + hh) * 128 + row] = bf16_rne(vj - __uint_as_float((unsigned)hj << 16));
        }
        #pragma unroll
        for (int rp = 0; rp < 4; ++rp) {
            int idx = t + rp * 256;
            WTh[136 * 128 + idx] = 0;
            WTl[136 * 128 + idx] = 0;
        }
        if (t < 128) {
            bias2[t] = bias[t];
        } else if (t < 136) {
            int z = t - 128;
            const float* av = (z < 4) ? a : a + 32;
            int hh = z & 3;
            float s = 0.f;
            for (int d = 0; d < 32; ++d) s = fmaf(bias[hh * 32 + d], av[d], s);
            bias2[128 + z] = s * L2E;
        } else if (t < 144) {
            bias2[t] = 0.f;
        }
    }
}

// ---------- proj: [h|ei|ej] = x @ [W|wa_i|wa_j]; 64 rows/block, grid 256 ----
__global__ __launch_bounds__(256, 1) void proj_kernel(
    const float* __restrict__ x,
    const unsigned short* __restrict__ WTg_h, const unsigned short* __restrict__ WTg_l,
    const float* __restrict__ bias2,
    unsigned short* __restrict__ hTh, float* __restrict__ eiT, float* __restrict__ ejT)
{
    __shared__ __align__(16) unsigned char smem[106496];  // xs 32K | WT 72K
    char* xls  = (char*)smem;
    char* wtls = (char*)smem + 32768;

    const int t = threadIdx.x, lane = t & 63, w = t >> 6;
    const int l16 = lane & 15, q = lane >> 4;
    const int nb = blockIdx.x * 64;
    const int b = nb >> 10, nloc = nb & 1023;

    {
        const char* gx = (const char*)(x + (size_t)nb * 128);
        int rh = lane >> 5, m = lane & 31;
        #pragma unroll
        for (int d = 0; d < 8; ++d) {
            int r = w * 16 + d * 2 + rh;
            int mg = m ^ (r & 7);
            gl_lds16(gx + (size_t)r * 512 + mg * 16, xls + (size_t)w * 8192 + d * 1024);
        }
    }
    {
        int rh = lane >> 4, m = lane & 15;
        #pragma unroll
        for (int d = 0; d < 18; ++d) {
            int n = w * 18 + d;
            if (n < 36) {
                int r = n * 4 + rh;
                gl_lds16((const char*)WTg_h + (size_t)r * 256 + (m ^ (r & 15)) * 16,
                         wtls + (size_t)n * 1024);
            } else {
                int r = (n - 36) * 4 + rh;
                gl_lds16((const char*)WTg_l + (size_t)r * 256 + (m ^ (r & 15)) * 16,
                         wtls + (size_t)n * 1024);
            }
        }
    }
    __syncthreads();

    float4v C[9];
    #pragma unroll
    for (int nt = 0; nt < 9; ++nt) C[nt] = (float4v){0.f, 0.f, 0.f, 0.f};

    #pragma unroll
    for (int ks = 0; ks < 4; ++ks) {
        short8 Ah, Al;
        {
            int r = w * 16 + l16;
            int c0 = (ks * 8 + q * 2) ^ (l16 & 7);
            int c1 = (ks * 8 + q * 2 + 1) ^ (l16 & 7);
            float4v x0 = *(const float4v*)(xls + (size_t)r * 512 + c0 * 16);
            float4v x1 = *(const float4v*)(xls + (size_t)r * 512 + c1 * 16);
            #pragma unroll
            for (int e = 0; e < 8; ++e) {
                float f = (e < 4) ? x0[e] : x1[e - 4];
                unsigned short hi = bf16_rne(f);
                Ah[e] = (short)hi;
                Al[e] = (short)bf16_rne(f - __uint_as_float((unsigned)hi << 16));
            }
        }
        #pragma unroll
        for (int nt = 0; nt < 9; ++nt) {
            const char* wb = wtls + (size_t)(nt * 16 + l16) * 256 + ((ks * 4 + q) ^ l16) * 16;
            short8 Bh = *(const short8*)wb;
            short8 Bl = *(const short8*)(wb + 36864);
            C[nt] = __builtin_amdgcn_mfma_f32_16x16x32_bf16(Ah, Bh, C[nt], 0, 0, 0);
            C[nt] = __builtin_amdgcn_mfma_f32_16x16x32_bf16(Ah, Bl, C[nt], 0, 0, 0);
            C[nt] = __builtin_amdgcn_mfma_f32_16x16x32_bf16(Al, Bh, C[nt], 0, 0, 0);
        }
    }

    {
        int node = nloc + w * 16 + q * 4;
        #pragma unroll
        for (int nt = 0; nt < 8; ++nt) {
            int col = nt * 16 + l16;
            float bv = bias2[col];
            ushort4v h4;
            #pragma unroll
            for (int r = 0; r < 4; ++r) h4[r] = bf16_rne(C[nt][r] + bv);
            *(ushort4v*)(hTh + (size_t)(b * HDc + col) * Ndim + node) = h4;
        }
        float bv = bias2[128 + l16];
        float4v v = {C[8][0] + bv, C[8][1] + bv, C[8][2] + bv, C[8][3] + bv};
        if (l16 < 4)
            *(float4v*)(eiT + (size_t)(b * Hh + l16) * Ndim + node) = v;
        else if (l16 < 8)
            *(float4v*)(ejT + (size_t)(b * Hh + (l16 - 4)) * Ndim + node) = v;
    }
}

// ---------- gat: chunked LDS residency; inner loop = pure LDS+VALU+MFMA -----
// block = 16 i-rows x 4 heads (wave = head), grid 1024, 4 blocks/CU.
// Per chunk (128 j): wave DMA-stages its head's hT slice + ej, barrier, compute.
__global__ __launch_bounds__(256, 4) void gat_kernel(
    const int* __restrict__ adj, const unsigned short* __restrict__ hTh,
    const float* __restrict__ eiT, const float* __restrict__ ejT,
    float* __restrict__ out)
{
    __shared__ __align__(16) unsigned char smem[36864];  // pk 2K | ej 2K | hT 32K
    unsigned int* pkl = (unsigned int*)smem;
    float* ejlf = (float*)(smem + 2048);                 // [4][128] f32
    char* hts = (char*)smem + 4096;                      // [4][32][16 chunks x 16B]

    const int t = threadIdx.x, lane = t & 63, w = t >> 6;
    const int L = blockIdx.x;
    const int b = (L & 7) + 8 * ((L >> 3) & 1);          // batch -> XCD pinning
    const int ibase = (L >> 4) * 16;
    const int i = lane & 15, q = lane >> 4;

    // ---- phase A: in-lane pack (adj is 0/1); wave w packs rows w*4..w*4+3
    {
        const int m = lane & 31, rh = lane >> 5;
        const int r0 = w * 4 + rh;
        const int r1 = w * 4 + 2 + rh;
        const int4v* s0 = (const int4v*)(adj + ((size_t)(b * Ndim + ibase + r0)) * Ndim + m * 32);
        const int4v* s1 = (const int4v*)(adj + ((size_t)(b * Ndim + ibase + r1)) * Ndim + m * 32);
        int4v va[8], vb[8];
        #pragma unroll
        for (int u = 0; u < 8; ++u) va[u] = __builtin_nontemporal_load(s0 + u);
        #pragma unroll
        for (int u = 0; u < 8; ++u) vb[u] = __builtin_nontemporal_load(s1 + u);
        unsigned wa = 0, wb_ = 0;
        #pragma unroll
        for (int u = 0; u < 8; ++u) {
            unsigned na  = (unsigned)(va[u][0] | (va[u][1] << 1) | (va[u][2] << 2) | (va[u][3] << 3));
            unsigned nb_ = (unsigned)(vb[u][0] | (vb[u][1] << 1) | (vb[u][2] << 2) | (vb[u][3] << 3));
            wa  |= na  << (4 * u);
            wb_ |= nb_ << (4 * u);
        }
        pkl[r0 * 32 + ((m + r0) & 31)] = wa;   // +row rotation kills bank alias
        pkl[r1 * 32 + ((m + r1) & 31)] = wb_;
    }
    const float my_ei = eiT[(size_t)(b * Hh + w) * Ndim + ibase + i];

    const char* ghh = (const char*)(hTh + (size_t)(b * HDc + w * 32) * Ndim);
    const char* gej = (const char*)(ejT + (size_t)(b * Hh) * Ndim);
    const int drow = lane >> 4;          // DMA: row-within-instr
    const int p16  = lane & 15;          // DMA: LDS chunk position
    const char* hrow0 = hts + (w * 32 + i) * 256;        // n-tile 0 (d = i)
    const char* hrow1 = hts + (w * 32 + 16 + i) * 256;   // n-tile 1 (d = 16+i)
    const float* ejw = ejlf + w * 128;

    float4v C0 = {0.f, 0.f, 0.f, 0.f};
    float4v C1 = {0.f, 0.f, 0.f, 0.f};
    float den_a = 0.f, den_b = 0.f;
    __syncthreads();   // pk visible; phase-A vmem drained

    for (int ch = 0; ch < 8; ++ch) {
        if (ch) __syncthreads();   // prev compute done before buffer overwrite
        // ---- stage hT chunk: head w rows d=0..31, swizzled chunk p = c ^ (d&15)
        #pragma unroll
        for (int u = 0; u < 8; ++u) {
            int d = u * 4 + drow;
            int c = p16 ^ (d & 15);
            gl_lds16(ghh + (size_t)d * 2048 + ch * 256 + c * 16,
                     hts + (w * 32 + u * 4) * 256);
        }
        // ---- stage ej chunk (2 KB): waves 0,1 cover 2 heads each
        if (w < 2) {
            int hh = w * 2 + (lane >> 5);
            gl_lds16(gej + (size_t)hh * 4096 + ch * 512 + (lane & 31) * 16,
                     (char*)ejlf + w * 1024);
        }
        __syncthreads();   // vmcnt(0) drain = DMA completion

        // ---- compute 4 j-tiles from LDS only
        #pragma unroll
        for (int jtl = 0; jtl < 4; ++jtl) {
            const int jt = ch * 4 + jtl;
            const int pc = ((jtl * 4 + q) ^ i) * 16;
            short8 Bh0 = *(const short8*)(hrow0 + pc);
            short8 Bh1 = *(const short8*)(hrow1 + pc);
            float4v e0 = *(const float4v*)(ejw + jtl * 32 + q * 8);
            float4v e1 = *(const float4v*)(ejw + jtl * 32 + q * 8 + 4);
            unsigned bits = (pkl[i * 32 + ((jt + i) & 31)] >> (q * 8)) & 0xffu;

            float p[8];
            #pragma unroll
            for (int k = 0; k < 8; ++k) {
                float ev = (k < 4) ? e0[k] : e1[k - 4];
                float e = my_ei + ev;                 // already * log2e
                float sL = fmaxf(e, 0.2f * e);        // leaky = max(e, 0.2e)
                float pe = ((bits >> k) & 1u) ? __builtin_amdgcn_exp2f(sL) : 0.f;
                if (k & 1) den_b += pe; else den_a += pe;
                p[k] = pe;
            }
            union { __hip_bfloat162 h2[4]; short8 s8; } A;
            #pragma unroll
            for (int k2 = 0; k2 < 4; ++k2)
                A.h2[k2] = __float22bfloat162_rn(make_float2(p[2 * k2], p[2 * k2 + 1]));
            C0 = __builtin_amdgcn_mfma_f32_16x16x32_bf16(A.s8, Bh0, C0, 0, 0, 0);
            C1 = __builtin_amdgcn_mfma_f32_16x16x32_bf16(A.s8, Bh1, C1, 0, 0, 0);
        }
    }

    float den = den_a + den_b;
    den += __shfl_xor(den, 16);
    den += __shfl_xor(den, 32);

    // C/D layout: col = lane&15 (feature), row = q*4+reg (node)
    float* outp = out + ((size_t)(b * Ndim + ibase)) * HDc + w * 32 + i;
    #pragma unroll
    for (int reg = 0; reg < 4; ++reg) {
        int row = q * 4 + reg;
        float rd = 1.0f / __shfl(den, row, 64);
        outp[(size_t)row * HDc]      = C0[reg] * rd;
        outp[(size_t)row * HDc + 16] = C1[reg] * rd;
    }
}

extern "C" void kernel_launch(void* const* d_in, const int* in_sizes, int n_in,
                              void* d_out, int out_size, void* d_ws, size_t ws_size,
                              hipStream_t stream) {
    const float* x    = (const float*)d_in[0];
    const int*   adj  = (const int*)d_in[1];
    const float* W    = (const float*)d_in[2];
    const float* bias = (const float*)d_in[3];
    const float* a    = (const float*)d_in[4];
    float* out = (float*)d_out;

    // ws: hTh 4MB | eiT 256K | ejT 256K | WTh 36K | WTl 36K | bias2
    unsigned short* hTh = (unsigned short*)d_ws;
    float* eiT = (float*)(hTh + (size_t)Bdim * HDc * Ndim);
    float* ejT = eiT + (size_t)Bdim * Hh * Ndim;
    unsigned short* WTh = (unsigned short*)(ejT + (size_t)Bdim * Hh * Ndim);
    unsigned short* WTl = WTh + 144 * 128;
    float* bias2 = (float*)(WTl + 144 * 128);

    split_w_kernel<<<dim3(17), dim3(256), 0, stream>>>(W, bias, a, WTh, WTl, bias2);
    proj_kernel<<<dim3(256), dim3(256), 0, stream>>>(
        x, WTh, WTl, bias2, hTh, eiT, ejT);
    gat_kernel<<<dim3(1024), dim3(256), 0, stream>>>(
        adj, hTh, eiT, ejT, out);
}

// Round 9
// 156.638 us; speedup vs baseline: 1.2636x; 1.0615x over previous
//
#include <hip/hip_runtime.h>
#include <hip/hip_bf16.h>

#define Bdim 16
#define Ndim 1024
#define Hh   4
#define HDc  128
#define L2E  1.4426950408889634f

typedef float  float4v  __attribute__((ext_vector_type(4)));
typedef int    int4v    __attribute__((ext_vector_type(4)));
typedef short  short8   __attribute__((ext_vector_type(8)));
typedef unsigned short ushort4v __attribute__((ext_vector_type(4)));
typedef unsigned int   uint2v   __attribute__((ext_vector_type(2)));
typedef _Float16 f16x2 __attribute__((ext_vector_type(2)));
typedef _Float16 half8 __attribute__((ext_vector_type(8)));

__device__ __forceinline__ unsigned short bf16_rne(float f) {
    unsigned u = __float_as_uint(f);
    u = u + 0x7FFFu + ((u >> 16) & 1u);
    return (unsigned short)(u >> 16);
}
__device__ __forceinline__ unsigned short f16u(float f) {
    _Float16 h = (_Float16)f;
    union { _Float16 h; unsigned short u; } c; c.h = h; return c.u;
}
__device__ __forceinline__ void gl_lds16(const void* g, void* l) {
    __builtin_amdgcn_global_load_lds(
        (const __attribute__((address_space(1))) unsigned int*)g,
        (__attribute__((address_space(3))) unsigned int*)l, 16, 0, 0);
}
// p2 = max(EE*Ej2, FF*Fj2) & mask   (packed fp16, 4 VALU for 2 scores)
__device__ __forceinline__ unsigned pmax_mask(unsigned EE, unsigned FF,
                                              unsigned Ej, unsigned Fj, unsigned m) {
    union { unsigned u; f16x2 h; } a, b, c, d, r;
    a.u = EE; b.u = Ej; c.u = FF; d.u = Fj;
    r.h = __builtin_elementwise_max(a.h * b.h, c.h * d.h);
    return r.u & m;
}

// ---------- split_w: WT hi/lo [144][128] row-major + bias2[144] -------------
__global__ __launch_bounds__(256) void split_w_kernel(
    const float* __restrict__ W, const float* __restrict__ bias,
    const float* __restrict__ a,
    unsigned short* __restrict__ WTh, unsigned short* __restrict__ WTl,
    float* __restrict__ bias2)
{
    const int t = threadIdx.x, blk = blockIdx.x;
    if (blk < 16) {
        int r  = blk * 8 + (t >> 5);
        int k0 = (t & 31) * 4;
        #pragma unroll
        for (int j = 0; j < 4; ++j) {
            float f = W[(size_t)(k0 + j) * HDc + r];
            unsigned short hi = bf16_rne(f);
            WTh[r * 128 + k0 + j] = hi;
            WTl[r * 128 + k0 + j] = bf16_rne(f - __uint_as_float((unsigned)hi << 16));
        }
    } else {
        #pragma unroll
        for (int rep = 0; rep < 2; ++rep) {
            int task = t + rep * 256;
            int row = task >> 2, hh = task & 3;
            float si = 0.f, sj = 0.f;
            #pragma unroll
            for (int d4 = 0; d4 < 8; ++d4) {
                float4v wv = *(const float4v*)(W + (size_t)row * HDc + hh * 32 + d4 * 4);
                float4v av = *(const float4v*)(a + d4 * 4);
                float4v bv = *(const float4v*)(a + 32 + d4 * 4);
                #pragma unroll
                for (int kk = 0; kk < 4; ++kk) {
                    si = fmaf(wv[kk], av[kk], si);
                    sj = fmaf(wv[kk], bv[kk], sj);
                }
            }
            float vi = si * L2E, vj = sj * L2E;
            unsigned short hi = bf16_rne(vi);
            WTh[(128 + hh) * 128 + row] = hi;
            WTl[(128 + hh) * 128 + row] = bf16_rne(vi - __uint_as_float((unsigned)hi << 16));
            unsigned short hj = bf16_rne(vj);
            WTh[(132 + hh) * 128 + row] = hj;
            WTl[(132 + hh) * 128 + row] = bf16_rne(vj - __uint_as_float((unsigned)hj << 16));
        }
        #pragma unroll
        for (int rp = 0; rp < 4; ++rp) {
            int idx = t + rp * 256;
            WTh[136 * 128 + idx] = 0;
            WTl[136 * 128 + idx] = 0;
        }
        if (t < 128) {
            bias2[t] = bias[t];
        } else if (t < 136) {
            int z = t - 128;
            const float* av = (z < 4) ? a : a + 32;
            int hh = z & 3;
            float s = 0.f;
            for (int d = 0; d < 32; ++d) s = fmaf(bias[hh * 32 + d], av[d], s);
            bias2[128 + z] = s * L2E;
        } else if (t < 144) {
            bias2[t] = 0.f;
        }
    }
}

// ---------- proj: h (fp16, transposed) + per-node E/F score tables ----------
__global__ __launch_bounds__(256, 1) void proj_kernel(
    const float* __restrict__ x,
    const unsigned short* __restrict__ WTg_h, const unsigned short* __restrict__ WTg_l,
    const float* __restrict__ bias2,
    unsigned short* __restrict__ hT,
    unsigned short* __restrict__ eiE, unsigned short* __restrict__ eiF,
    unsigned short* __restrict__ ejE, unsigned short* __restrict__ ejF)
{
    __shared__ __align__(16) unsigned char smem[106496];  // xs 32K | WT 72K
    char* xls  = (char*)smem;
    char* wtls = (char*)smem + 32768;

    const int t = threadIdx.x, lane = t & 63, w = t >> 6;
    const int l16 = lane & 15, q = lane >> 4;
    const int nb = blockIdx.x * 64;
    const int b = nb >> 10, nloc = nb & 1023;

    {
        const char* gx = (const char*)(x + (size_t)nb * 128);
        int rh = lane >> 5, m = lane & 31;
        #pragma unroll
        for (int d = 0; d < 8; ++d) {
            int r = w * 16 + d * 2 + rh;
            int mg = m ^ (r & 7);
            gl_lds16(gx + (size_t)r * 512 + mg * 16, xls + (size_t)w * 8192 + d * 1024);
        }
    }
    {
        int rh = lane >> 4, m = lane & 15;
        #pragma unroll
        for (int d = 0; d < 18; ++d) {
            int n = w * 18 + d;
            if (n < 36) {
                int r = n * 4 + rh;
                gl_lds16((const char*)WTg_h + (size_t)r * 256 + (m ^ (r & 15)) * 16,
                         wtls + (size_t)n * 1024);
            } else {
                int r = (n - 36) * 4 + rh;
                gl_lds16((const char*)WTg_l + (size_t)r * 256 + (m ^ (r & 15)) * 16,
                         wtls + (size_t)n * 1024);
            }
        }
    }
    __syncthreads();

    float4v C[9];
    #pragma unroll
    for (int nt = 0; nt < 9; ++nt) C[nt] = (float4v){0.f, 0.f, 0.f, 0.f};

    #pragma unroll
    for (int ks = 0; ks < 4; ++ks) {
        short8 Ah, Al;
        {
            int r = w * 16 + l16;
            int c0 = (ks * 8 + q * 2) ^ (l16 & 7);
            int c1 = (ks * 8 + q * 2 + 1) ^ (l16 & 7);
            float4v x0 = *(const float4v*)(xls + (size_t)r * 512 + c0 * 16);
            float4v x1 = *(const float4v*)(xls + (size_t)r * 512 + c1 * 16);
            #pragma unroll
            for (int e = 0; e < 8; ++e) {
                float f = (e < 4) ? x0[e] : x1[e - 4];
                unsigned short hi = bf16_rne(f);
                Ah[e] = (short)hi;
                Al[e] = (short)bf16_rne(f - __uint_as_float((unsigned)hi << 16));
            }
        }
        #pragma unroll
        for (int nt = 0; nt < 9; ++nt) {
            const char* wb = wtls + (size_t)(nt * 16 + l16) * 256 + ((ks * 4 + q) ^ l16) * 16;
            short8 Bh = *(const short8*)wb;
            short8 Bl = *(const short8*)(wb + 36864);
            C[nt] = __builtin_amdgcn_mfma_f32_16x16x32_bf16(Ah, Bh, C[nt], 0, 0, 0);
            C[nt] = __builtin_amdgcn_mfma_f32_16x16x32_bf16(Ah, Bl, C[nt], 0, 0, 0);
            C[nt] = __builtin_amdgcn_mfma_f32_16x16x32_bf16(Al, Bh, C[nt], 0, 0, 0);
        }
    }

    {
        int node = nloc + w * 16 + q * 4;
        #pragma unroll
        for (int nt = 0; nt < 8; ++nt) {
            int col = nt * 16 + l16;
            float bv = bias2[col];
            ushort4v h4;
            #pragma unroll
            for (int r = 0; r < 4; ++r) h4[r] = f16u(C[nt][r] + bv);
            *(ushort4v*)(hT + (size_t)(b * HDc + col) * Ndim + node) = h4;
        }
        // e-columns -> per-node E/F tables (exp factored out of gat inner loop)
        float bv = bias2[128 + l16];
        if (l16 < 8) {
            int hh = l16 & 3;
            ushort4v Ev, Fv;
            #pragma unroll
            for (int r = 0; r < 4; ++r) {
                float v = C[8][r] + bv;                 // already * log2e
                Ev[r] = f16u(__builtin_amdgcn_exp2f(v));
                Fv[r] = f16u(__builtin_amdgcn_exp2f(0.2f * v));
            }
            size_t off = (size_t)(b * Hh + hh) * Ndim + node;
            if (l16 < 4) { *(ushort4v*)(eiE + off) = Ev; *(ushort4v*)(eiF + off) = Fv; }
            else         { *(ushort4v*)(ejE + off) = Ev; *(ushort4v*)(ejF + off) = Fv; }
        }
    }
}

// ---------- gat: packed-fp16 scores (no exp), f16 MFMA PV + MFMA den --------
// block = 16 i-rows x 4 heads (wave = head), grid 1024, 4 blocks/CU.
__global__ __launch_bounds__(256, 4) void gat_kernel(
    const int* __restrict__ adj, const unsigned short* __restrict__ hT,
    const unsigned short* __restrict__ eiE, const unsigned short* __restrict__ eiF,
    const unsigned short* __restrict__ ejE, const unsigned short* __restrict__ ejF,
    float* __restrict__ out)
{
    __shared__ __align__(16) unsigned char smem[40960]; // pk 2K|lut 128B|ej 4K|hT 32K
    unsigned int* pkl = (unsigned int*)smem;
    unsigned int* lut = (unsigned int*)(smem + 2048);
    char* ejl = (char*)smem + 4096;
    char* hts = (char*)smem + 8192;

    const int t = threadIdx.x, lane = t & 63, w = t >> 6;
    const int L = blockIdx.x;
    const int b = (L & 7) + 8 * ((L >> 3) & 1);          // batch -> XCD pinning
    const int ibase = (L >> 4) * 16;
    const int i = lane & 15, q = lane >> 4;

    // ---- phase A: in-lane pack (adj is 0/1); wave w packs rows w*4..w*4+3
    {
        const int m = lane & 31, rh = lane >> 5;
        const int r0 = w * 4 + rh;
        const int r1 = w * 4 + 2 + rh;
        const int4v* s0 = (const int4v*)(adj + ((size_t)(b * Ndim + ibase + r0)) * Ndim + m * 32);
        const int4v* s1 = (const int4v*)(adj + ((size_t)(b * Ndim + ibase + r1)) * Ndim + m * 32);
        int4v va[8], vb[8];
        #pragma unroll
        for (int u = 0; u < 8; ++u) va[u] = __builtin_nontemporal_load(s0 + u);
        #pragma unroll
        for (int u = 0; u < 8; ++u) vb[u] = __builtin_nontemporal_load(s1 + u);
        unsigned wa = 0, wb_ = 0;
        #pragma unroll
        for (int u = 0; u < 8; ++u) {
            unsigned na  = (unsigned)(va[u][0] | (va[u][1] << 1) | (va[u][2] << 2) | (va[u][3] << 3));
            unsigned nb_ = (unsigned)(vb[u][0] | (vb[u][1] << 1) | (vb[u][2] << 2) | (vb[u][3] << 3));
            wa  |= na  << (4 * u);
            wb_ |= nb_ << (4 * u);
        }
        pkl[r0 * 32 + ((m + r0) & 31)] = wa;   // +row rotation kills bank alias
        pkl[r1 * 32 + ((m + r1) & 31)] = wb_;
    }
    // ---- 16-entry mask LUT: 2 adj bits -> half2 bitmask pair (b64 read, conflict-free)
    if (t < 16) {
        lut[t * 2]     = ((t & 1) ? 0xFFFFu : 0u) | ((t & 2) ? 0xFFFF0000u : 0u);
        lut[t * 2 + 1] = ((t & 4) ? 0xFFFFu : 0u) | ((t & 8) ? 0xFFFF0000u : 0u);
    }
    // ---- Ei/Fi broadcast constants (per lane: node ibase+i, head w)
    const size_t eidx = (size_t)(b * Hh + w) * Ndim + ibase + i;
    const unsigned Eu = eiE[eidx], Fu = eiF[eidx];
    const unsigned EE = Eu | (Eu << 16);
    const unsigned FF = Fu | (Fu << 16);
    __syncthreads();   // pk+lut visible; phase-A vmem drained

    const char* ghh = (const char*)(hT + (size_t)(b * HDc + w * 32) * Ndim);
    const int drow = lane >> 4;
    const int p16  = lane & 15;
    // ej DMA source: lanes 0-15 stage ejE chunk, 16-31 ejF, 32-63 duplicate
    const char* gE = (const char*)(ejE + (size_t)(b * Hh + w) * Ndim);
    const char* gF = (const char*)(ejF + (size_t)(b * Hh + w) * Ndim);
    const int l5 = lane & 31;
    const char* esrc = (l5 < 16) ? gE + l5 * 16 : gF + (l5 - 16) * 16;

    const char* hrow0 = hts + (w * 32 + i) * 256;
    const char* hrow1 = hrow0 + 16 * 256;
    const char* ejw   = ejl + w * 1024;
    const uint2v* lut2 = (const uint2v*)lut;

    half8 ONES;
    #pragma unroll
    for (int e = 0; e < 8; ++e) ONES[e] = (_Float16)1.0f;

    float4v C0 = {0.f, 0.f, 0.f, 0.f};
    float4v C1 = {0.f, 0.f, 0.f, 0.f};
    float4v C2 = {0.f, 0.f, 0.f, 0.f};   // den via ones-column MFMA

    for (int ch = 0; ch < 8; ++ch) {
        if (ch) __syncthreads();
        // stage hT chunk (8 KB/wave, swizzled) + ej chunk (512 B/wave)
        #pragma unroll
        for (int u = 0; u < 8; ++u) {
            int d = u * 4 + drow;
            int c = p16 ^ (d & 15);
            gl_lds16(ghh + (size_t)d * 2048 + ch * 256 + c * 16,
                     hts + (w * 32 + u * 4) * 256);
        }
        gl_lds16(esrc + ch * 256, ejl + w * 1024);
        __syncthreads();   // vmcnt(0) drain = DMA completion

        #pragma unroll
        for (int jtl = 0; jtl < 4; ++jtl) {
            const int jt = ch * 4 + jtl;
            const int sb = jtl * 4 + q;
            half8 Bh0 = *(const half8*)(hrow0 + ((sb ^ i) << 4));
            half8 Bh1 = *(const half8*)(hrow1 + ((sb ^ i) << 4));
            int4v Ejp = *(const int4v*)(ejw + (sb << 4));
            int4v Fjp = *(const int4v*)(ejw + 256 + (sb << 4));
            unsigned bits = (pkl[i * 32 + ((jt + i) & 31)] >> (q * 8)) & 0xffu;
            uint2v m0 = lut2[bits & 15];
            uint2v m1 = lut2[bits >> 4];

            union { unsigned u[4]; half8 v; } A;
            A.u[0] = pmax_mask(EE, FF, (unsigned)Ejp[0], (unsigned)Fjp[0], m0[0]);
            A.u[1] = pmax_mask(EE, FF, (unsigned)Ejp[1], (unsigned)Fjp[1], m0[1]);
            A.u[2] = pmax_mask(EE, FF, (unsigned)Ejp[2], (unsigned)Fjp[2], m1[0]);
            A.u[3] = pmax_mask(EE, FF, (unsigned)Ejp[3], (unsigned)Fjp[3], m1[1]);

            C0 = __builtin_amdgcn_mfma_f32_16x16x32_f16(A.v, Bh0, C0, 0, 0, 0);
            C1 = __builtin_amdgcn_mfma_f32_16x16x32_f16(A.v, Bh1, C1, 0, 0, 0);
            C2 = __builtin_amdgcn_mfma_f32_16x16x32_f16(A.v, ONES, C2, 0, 0, 0);
        }
    }

    // C/D layout: col = lane&15 (feature), row = q*4+reg (node).
    // C2 rows carry den for the SAME rows -> no shuffles needed.
    float* outp = out + ((size_t)(b * Ndim + ibase)) * HDc + w * 32 + i;
    #pragma unroll
    for (int reg = 0; reg < 4; ++reg) {
        int row = q * 4 + reg;
        float rd = 1.0f / C2[reg];
        outp[(size_t)row * HDc]      = C0[reg] * rd;
        outp[(size_t)row * HDc + 16] = C1[reg] * rd;
    }
}

extern "C" void kernel_launch(void* const* d_in, const int* in_sizes, int n_in,
                              void* d_out, int out_size, void* d_ws, size_t ws_size,
                              hipStream_t stream) {
    const float* x    = (const float*)d_in[0];
    const int*   adj  = (const int*)d_in[1];
    const float* W    = (const float*)d_in[2];
    const float* bias = (const float*)d_in[3];
    const float* a    = (const float*)d_in[4];
    float* out = (float*)d_out;

    // ws: hT 4MB | eiE/eiF/ejE/ejF 128KB ea | WTh 36K | WTl 36K | bias2
    unsigned short* hT  = (unsigned short*)d_ws;
    unsigned short* eiE = hT  + (size_t)Bdim * HDc * Ndim;
    unsigned short* eiF = eiE + (size_t)Bdim * Hh * Ndim;
    unsigned short* ejE = eiF + (size_t)Bdim * Hh * Ndim;
    unsigned short* ejF = ejE + (size_t)Bdim * Hh * Ndim;
    unsigned short* WTh = ejF + (size_t)Bdim * Hh * Ndim;
    unsigned short* WTl = WTh + 144 * 128;
    float* bias2 = (float*)(WTl + 144 * 128);

    split_w_kernel<<<dim3(17), dim3(256), 0, stream>>>(W, bias, a, WTh, WTl, bias2);
    proj_kernel<<<dim3(256), dim3(256), 0, stream>>>(
        x, WTh, WTl, bias2, hT, eiE, eiF, ejE, ejF);
    gat_kernel<<<dim3(1024), dim3(256), 0, stream>>>(
        adj, hT, eiE, eiF, ejE, ejF, out);
}